// Round 9
// baseline (41.506 us; speedup 1.0000x reference)
//
#include <hip/hip_runtime.h>

#define BATCH   8192
#define FBINS   2048
#define KSLOTS  6

#define HTHREADS 512
#define HWAVES   8
#define HBLOCKS  1024
#define TILES    8
#define TILE_F4  512                     // float4 per array per tile (8 KB)
#define WTILE_F4 (TILE_F4 / HWAVES)      // 64 per wave per array per tile = 1 DMA
#define BLK_F4   (TILES * TILE_F4)       // 4096 per array per block
// HBLOCKS * BLK_F4 = 1024*4096 = 4194304 = BATCH*FBINS/4  ✓

#define RBLOCKS   (BATCH / HTHREADS)     // 16
#define TOTBLOCKS (HBLOCKS + RBLOCKS)    // 1040

#define LS   0.1f
#define LBW  0.05f
#define BWMAX 4.0f
#define LAP  0.5f
#define LPK  0.3f
#define LUM  0.1f

__device__ __forceinline__ void gload16(const float4* g, float4* l) {
    // async global->LDS DMA, 16 B/lane; global src per-lane, LDS dest wave-uniform
    __builtin_amdgcn_global_load_lds(
        (const __attribute__((address_space(1))) void*)g,
        (__attribute__((address_space(3))) void*)l, 16, 0, 0);
}

__device__ __forceinline__ float huber4(float4 a, float4 b) {
    float s = 0.f;
    { float e = a.x - b.x; float ab = fabsf(e); s += (ab < 1.f) ? 0.5f * e * e : ab - 0.5f; }
    { float e = a.y - b.y; float ab = fabsf(e); s += (ab < 1.f) ? 0.5f * e * e : ab - 0.5f; }
    { float e = a.z - b.z; float ab = fabsf(e); s += (ab < 1.f) ? 0.5f * e * e : ab - 0.5f; }
    { float e = a.w - b.w; float ab = fabsf(e); s += (ab < 1.f) ? 0.5f * e * e : ab - 0.5f; }
    return s;
}

// ws layout: accs[0..7] doubles (0=huber, 1..7=row terms), counter uint at +64.
// All zeroed by hipMemsetAsync each call.
// Row acc order: 1 amps, 2 bw, 3 ap, 4 peaks, 5 mask, 6 um_cnt, 7 um_amps.
__global__ __launch_bounds__(HTHREADS) void fused_all(
    const float* __restrict__ pred,  const float* __restrict__ tgt,
    const float* __restrict__ cfs,   const float* __restrict__ amps,
    const float* __restrict__ bws,   const float* __restrict__ expn,
    const float* __restrict__ offs,  const float* __restrict__ gt_cfs,
    const float* __restrict__ gt_amps, const float* __restrict__ gt_bws,
    const float* __restrict__ gt_off, const float* __restrict__ gt_exp,
    const float* __restrict__ mask,
    double* __restrict__ accs, unsigned int* __restrict__ counter,
    float* __restrict__ out)
{
    __shared__ float4 ldsA[2][TILE_F4];   // 16 KB
    __shared__ float4 ldsB[2][TILE_F4];   // 16 KB
    __shared__ float  wred[HWAVES][8];

    const int tid  = threadIdx.x;
    const int wave = tid >> 6;
    const int lane = tid & 63;

    if (blockIdx.x < HBLOCKS) {
        // ---------- Huber path: barrier-free per-wave DMA pipeline ----------
        const float4* __restrict__ a4 = (const float4*)pred;
        const float4* __restrict__ b4 = (const float4*)tgt;
        const int woff  = wave * WTILE_F4;           // wave-private LDS slice
        const int gbase = blockIdx.x * BLK_F4 + woff + lane;

        // prologue: tile 0 (1 DMA per array per wave)
        gload16(a4 + gbase, &ldsA[0][woff]);
        gload16(b4 + gbase, &ldsB[0][woff]);

        float ssum = 0.f;
        #pragma unroll
        for (int t = 0; t < TILES; t++) {
            const int buf = t & 1;
            if (t + 1 < TILES) {
                gload16(a4 + gbase + (t + 1) * TILE_F4, &ldsA[buf ^ 1][woff]);
                gload16(b4 + gbase + (t + 1) * TILE_F4, &ldsB[buf ^ 1][woff]);
                asm volatile("s_waitcnt vmcnt(2)" ::: "memory");
            } else {
                asm volatile("s_waitcnt vmcnt(0)" ::: "memory");
            }
            __builtin_amdgcn_sched_barrier(0);

            float4 a = ldsA[buf][woff + lane];
            float4 b = ldsB[buf][woff + lane];
            ssum += huber4(a, b);
        }

        #pragma unroll
        for (int o = 32; o > 0; o >>= 1)
            ssum += __shfl_down(ssum, o, 64);
        if (lane == 0) wred[wave][0] = ssum;
        __syncthreads();
        if (tid == 0) {
            float t = 0.f;
            #pragma unroll
            for (int w = 0; w < HWAVES; w++) t += wred[w][0];
            __hip_atomic_fetch_add(&accs[0], (double)t,
                                   __ATOMIC_RELAXED, __HIP_MEMORY_SCOPE_AGENT);
        }
    } else {
        // ---------- Row-matching path ----------
        const int rb = blockIdx.x - HBLOCKS;
        const int b = rb * HTHREADS + tid;

        float acc[7];   // amps, bw, ap, peaks, mask, um_cnt, um_amps
        #pragma unroll
        for (int c = 0; c < 7; c++) acc[c] = 0.f;

        {
            float c[KSLOTS], a[KSLOTS], w[KSLOTS];
            float gc[KSLOTS], ga[KSLOTS], gw[KSLOTS], m[KSLOTS];
            #pragma unroll
            for (int i = 0; i < KSLOTS; i++) {
                c[i]  = cfs[b * KSLOTS + i];
                a[i]  = amps[b * KSLOTS + i];
                w[i]  = bws[b * KSLOTS + i];
                gc[i] = gt_cfs[b * KSLOTS + i];
                ga[i] = gt_amps[b * KSLOTS + i];
                gw[i] = gt_bws[b * KSLOTS + i];
                m[i]  = mask[b * KSLOTS + i];
            }

            bool used[KSLOTS];
            #pragma unroll
            for (int i = 0; i < KSLOTS; i++) used[i] = false;

            // Greedy over GT slots (lax.scan order); strict < = first-min
            // tie-break, matching jnp.argmin.
            for (int j = 0; j < KSLOTS; j++) {
                if (m[j] > 0.5f) {
                    int best = -1;
                    float bd = 3.402823e+38f;
                    #pragma unroll
                    for (int i = 0; i < KSLOTS; i++) {
                        if (!used[i]) {
                            float d = fabsf(gc[j] - c[i]);
                            if (d < bd) { bd = d; best = i; }
                        }
                    }
                    used[best] = true;
                    float dc = c[best] - gc[j];
                    float da = a[best] - ga[j];
                    float dw = w[best] - gw[j];
                    acc[3] += dc * dc + da * da + dw * dw;
                    acc[4] += 1.f;
                }
            }

            #pragma unroll
            for (int i = 0; i < KSLOTS; i++) {
                acc[0] += a[i];
                float ex = fmaxf(w[i] - BWMAX, 0.f);
                acc[1] += ex * ex;
                if (!used[i]) { acc[5] += 1.f; acc[6] += a[i]; }
            }

            float de = expn[b] - gt_exp[b];
            float dof = offs[b] - gt_off[b];
            acc[2] = de * de + dof * dof;
        }

        #pragma unroll
        for (int c = 0; c < 7; c++) {
            float v = acc[c];
            #pragma unroll
            for (int o = 32; o > 0; o >>= 1)
                v += __shfl_down(v, o, 64);
            acc[c] = v;
        }
        if (lane == 0) {
            #pragma unroll
            for (int c = 0; c < 7; c++) wred[wave][c] = acc[c];
        }
        __syncthreads();
        if (tid < 7) {
            float t = 0.f;
            #pragma unroll
            for (int w = 0; w < HWAVES; w++) t += wred[w][tid];
            __hip_atomic_fetch_add(&accs[1 + tid], (double)t,
                                   __ATOMIC_RELAXED, __HIP_MEMORY_SCOPE_AGENT);
        }
    }

    // ---------- completion: last block finalizes (atomics only, no fences) ----------
    if (tid == 0) {
        // ensure this block's accumulator RMWs have completed at the
        // coherence point before the counter RMW issues
        asm volatile("s_waitcnt vmcnt(0)" ::: "memory");
        unsigned int prev = __hip_atomic_fetch_add(counter, 1u,
                               __ATOMIC_RELAXED, __HIP_MEMORY_SCOPE_AGENT);
        if (prev == TOTBLOCKS - 1) {
            // counter RMWs serialize at the coherence point; ours is last, so
            // every block's acc adds (which completed before its counter RMW)
            // are visible to agent-scope atomic loads.
            double v[8];
            #pragma unroll
            for (int i = 0; i < 8; i++)
                v[i] = __hip_atomic_load(&accs[i], __ATOMIC_RELAXED,
                                         __HIP_MEMORY_SCOPE_AGENT);
            double l_recon  = v[0] / ((double)BATCH * FBINS);
            double l_sparse = v[1] / ((double)BATCH * KSLOTS);
            double l_bw     = v[2] / ((double)BATCH * KSLOTS);
            double l_ap     = v[3] / (double)BATCH;
            double n_real   = v[5] > 1.0 ? v[5] : 1.0;
            double l_peaks  = v[4] / n_real;
            double n_um     = v[6] > 1.0 ? v[6] : 1.0;
            double l_um     = v[7] / n_um;
            double total = l_recon + (double)LS * l_sparse + (double)LBW * l_bw
                         + (double)LAP * l_ap + (double)LPK * l_peaks
                         + (double)LUM * l_um;
            out[0] = (float)total;
        }
    }
}

extern "C" void kernel_launch(void* const* d_in, const int* in_sizes, int n_in,
                              void* d_out, int out_size, void* d_ws, size_t ws_size,
                              hipStream_t stream) {
    const float* pred_psd = (const float*)d_in[0];
    const float* true_psd = (const float*)d_in[1];
    const float* cfs      = (const float*)d_in[2];
    const float* amps     = (const float*)d_in[3];
    const float* bws      = (const float*)d_in[4];
    const float* expn     = (const float*)d_in[5];
    const float* offs     = (const float*)d_in[6];
    const float* gt_cfs   = (const float*)d_in[7];
    const float* gt_amps  = (const float*)d_in[8];
    const float* gt_bws   = (const float*)d_in[9];
    const float* gt_off   = (const float*)d_in[10];
    const float* gt_exp   = (const float*)d_in[11];
    const float* mask     = (const float*)d_in[12];
    float* out = (float*)d_out;

    // ws: accs[0..7] doubles (64 B), counter uint at +64; zero 128 B per call
    double* accs = (double*)d_ws;
    unsigned int* counter = (unsigned int*)((char*)d_ws + 64);

    hipMemsetAsync(d_ws, 0, 128, stream);
    fused_all<<<TOTBLOCKS, HTHREADS, 0, stream>>>(
        pred_psd, true_psd, cfs, amps, bws, expn, offs,
        gt_cfs, gt_amps, gt_bws, gt_off, gt_exp, mask, accs, counter, out);
}

// Round 10
// 30.432 us; speedup vs baseline: 1.3639x; 1.3639x over previous
//
#include <hip/hip_runtime.h>

#define BATCH   8192
#define FBINS   2048
#define KSLOTS  6

#define HTHREADS 256
#define HWAVES   4
#define HBLOCKS  2048
#define TILES    8
#define TILE_F4  256                     // float4 per array per tile (4 KB)
#define WTILE_F4 (TILE_F4 / HWAVES)      // 64 per wave per array per tile = 1 DMA
#define BLK_F4   (TILES * TILE_F4)       // 2048 per array per block
// HBLOCKS * BLK_F4 = 2048*2048 = 4194304 = BATCH*FBINS/4  ✓

#define RBLOCKS   (BATCH / HTHREADS)     // 32
#define TOTBLOCKS (HBLOCKS + RBLOCKS)    // 2080

#define LS   0.1f
#define LBW  0.05f
#define BWMAX 4.0f
#define LAP  0.5f
#define LPK  0.3f
#define LUM  0.1f

__device__ __forceinline__ void gload16(const float4* g, float4* l) {
    // async global->LDS DMA, 16 B/lane; global src per-lane, LDS dest wave-uniform
    __builtin_amdgcn_global_load_lds(
        (const __attribute__((address_space(1))) void*)g,
        (__attribute__((address_space(3))) void*)l, 16, 0, 0);
}

__device__ __forceinline__ float huber4(float4 a, float4 b) {
    float s = 0.f;
    { float e = a.x - b.x; float ab = fabsf(e); s += (ab < 1.f) ? 0.5f * e * e : ab - 0.5f; }
    { float e = a.y - b.y; float ab = fabsf(e); s += (ab < 1.f) ? 0.5f * e * e : ab - 0.5f; }
    { float e = a.z - b.z; float ab = fabsf(e); s += (ab < 1.f) ? 0.5f * e * e : ab - 0.5f; }
    { float e = a.w - b.w; float ab = fabsf(e); s += (ab < 1.f) ? 0.5f * e * e : ab - 0.5f; }
    return s;
}

// ---------------- Kernel 1: pipelined-DMA huber partials + row partials ----------------
// rpart layout: rpart[7 * rb + c]:
//   0 amps_sum, 1 bw_sum, 2 ap_sum, 3 peaks_sum, 4 mask_sum, 5 um_cnt, 6 um_amps
__global__ __launch_bounds__(HTHREADS) void fused_partial(
    const float* __restrict__ pred,  const float* __restrict__ tgt,
    const float* __restrict__ cfs,   const float* __restrict__ amps,
    const float* __restrict__ bws,   const float* __restrict__ expn,
    const float* __restrict__ offs,  const float* __restrict__ gt_cfs,
    const float* __restrict__ gt_amps, const float* __restrict__ gt_bws,
    const float* __restrict__ gt_off, const float* __restrict__ gt_exp,
    const float* __restrict__ mask,
    float* __restrict__ hpart, float* __restrict__ rpart)
{
    __shared__ float4 ldsA[2][TILE_F4];   // 8 KB
    __shared__ float4 ldsB[2][TILE_F4];   // 8 KB
    __shared__ float  wred[HWAVES][8];

    const int tid  = threadIdx.x;
    const int wave = tid >> 6;
    const int lane = tid & 63;

    if (blockIdx.x < HBLOCKS) {
        // ---------- Huber path: barrier-free per-wave DMA pipeline ----------
        const float4* __restrict__ a4 = (const float4*)pred;
        const float4* __restrict__ b4 = (const float4*)tgt;
        const int woff  = wave * WTILE_F4;           // wave-private LDS slice
        const int gbase = blockIdx.x * BLK_F4 + woff + lane;

        // prologue: tile 0 (1 DMA per array per wave)
        gload16(a4 + gbase, &ldsA[0][woff]);
        gload16(b4 + gbase, &ldsB[0][woff]);

        float ssum = 0.f;
        #pragma unroll
        for (int t = 0; t < TILES; t++) {
            const int buf = t & 1;
            if (t + 1 < TILES) {
                gload16(a4 + gbase + (t + 1) * TILE_F4, &ldsA[buf ^ 1][woff]);
                gload16(b4 + gbase + (t + 1) * TILE_F4, &ldsB[buf ^ 1][woff]);
                asm volatile("s_waitcnt vmcnt(2)" ::: "memory");
            } else {
                asm volatile("s_waitcnt vmcnt(0)" ::: "memory");
            }
            __builtin_amdgcn_sched_barrier(0);

            float4 a = ldsA[buf][woff + lane];
            float4 b = ldsB[buf][woff + lane];
            ssum += huber4(a, b);
        }

        #pragma unroll
        for (int o = 32; o > 0; o >>= 1)
            ssum += __shfl_down(ssum, o, 64);
        if (lane == 0) wred[wave][0] = ssum;
        __syncthreads();
        if (tid == 0) {
            float t = 0.f;
            #pragma unroll
            for (int w = 0; w < HWAVES; w++) t += wred[w][0];
            hpart[blockIdx.x] = t;
        }
        return;
    }

    // ---------- Row-matching path ----------
    const int rb = blockIdx.x - HBLOCKS;
    const int b = rb * HTHREADS + tid;

    float acc[7];   // amps, bw, ap, peaks, mask, um_cnt, um_amps
    #pragma unroll
    for (int c = 0; c < 7; c++) acc[c] = 0.f;

    {
        float c[KSLOTS], a[KSLOTS], w[KSLOTS];
        float gc[KSLOTS], ga[KSLOTS], gw[KSLOTS], m[KSLOTS];
        #pragma unroll
        for (int i = 0; i < KSLOTS; i++) {
            c[i]  = cfs[b * KSLOTS + i];
            a[i]  = amps[b * KSLOTS + i];
            w[i]  = bws[b * KSLOTS + i];
            gc[i] = gt_cfs[b * KSLOTS + i];
            ga[i] = gt_amps[b * KSLOTS + i];
            gw[i] = gt_bws[b * KSLOTS + i];
            m[i]  = mask[b * KSLOTS + i];
        }

        bool used[KSLOTS];
        #pragma unroll
        for (int i = 0; i < KSLOTS; i++) used[i] = false;

        // Greedy over GT slots (lax.scan order); strict < = first-min
        // tie-break, matching jnp.argmin.
        for (int j = 0; j < KSLOTS; j++) {
            if (m[j] > 0.5f) {
                int best = -1;
                float bd = 3.402823e+38f;
                #pragma unroll
                for (int i = 0; i < KSLOTS; i++) {
                    if (!used[i]) {
                        float d = fabsf(gc[j] - c[i]);
                        if (d < bd) { bd = d; best = i; }
                    }
                }
                used[best] = true;
                float dc = c[best] - gc[j];
                float da = a[best] - ga[j];
                float dw = w[best] - gw[j];
                acc[3] += dc * dc + da * da + dw * dw;
                acc[4] += 1.f;
            }
        }

        #pragma unroll
        for (int i = 0; i < KSLOTS; i++) {
            acc[0] += a[i];
            float ex = fmaxf(w[i] - BWMAX, 0.f);
            acc[1] += ex * ex;
            if (!used[i]) { acc[5] += 1.f; acc[6] += a[i]; }
        }

        float de = expn[b] - gt_exp[b];
        float dof = offs[b] - gt_off[b];
        acc[2] = de * de + dof * dof;
    }

    #pragma unroll
    for (int c = 0; c < 7; c++) {
        float v = acc[c];
        #pragma unroll
        for (int o = 32; o > 0; o >>= 1)
            v += __shfl_down(v, o, 64);
        acc[c] = v;
    }
    if (lane == 0) {
        #pragma unroll
        for (int c = 0; c < 7; c++) wred[wave][c] = acc[c];
    }
    __syncthreads();
    if (tid < 7) {
        float t = 0.f;
        #pragma unroll
        for (int w = 0; w < HWAVES; w++) t += wred[w][tid];
        rpart[7 * rb + tid] = t;
    }
}

// ---------------- Kernel 2: finalize (1 block) ----------------
__global__ __launch_bounds__(256) void finalize(
    const float* __restrict__ hpart, const float* __restrict__ rpart,
    float* __restrict__ out)
{
    __shared__ double sm[256];
    double s = 0.0;
    #pragma unroll
    for (int r = 0; r < HBLOCKS / 256; r++)
        s += (double)hpart[r * 256 + threadIdx.x];
    sm[threadIdx.x] = s;
    __syncthreads();
    for (int o = 128; o > 0; o >>= 1) {
        if (threadIdx.x < o) sm[threadIdx.x] += sm[threadIdx.x + o];
        __syncthreads();
    }

    if (threadIdx.x == 0) {
        double huber_total = sm[0];
        double acc[7];
        for (int c = 0; c < 7; c++) acc[c] = 0.0;
        for (int blk = 0; blk < RBLOCKS; blk++)
            for (int c = 0; c < 7; c++)
                acc[c] += (double)rpart[7 * blk + c];

        double l_recon  = huber_total / ((double)BATCH * FBINS);
        double l_sparse = acc[0] / ((double)BATCH * KSLOTS);
        double l_bw     = acc[1] / ((double)BATCH * KSLOTS);
        double l_ap     = acc[2] / (double)BATCH;
        double n_real   = acc[4] > 1.0 ? acc[4] : 1.0;
        double l_peaks  = acc[3] / n_real;
        double n_um     = acc[5] > 1.0 ? acc[5] : 1.0;
        double l_um     = acc[6] / n_um;

        double total = l_recon + (double)LS * l_sparse + (double)LBW * l_bw
                     + (double)LAP * l_ap + (double)LPK * l_peaks + (double)LUM * l_um;
        out[0] = (float)total;
    }
}

extern "C" void kernel_launch(void* const* d_in, const int* in_sizes, int n_in,
                              void* d_out, int out_size, void* d_ws, size_t ws_size,
                              hipStream_t stream) {
    const float* pred_psd = (const float*)d_in[0];
    const float* true_psd = (const float*)d_in[1];
    const float* cfs      = (const float*)d_in[2];
    const float* amps     = (const float*)d_in[3];
    const float* bws      = (const float*)d_in[4];
    const float* expn     = (const float*)d_in[5];
    const float* offs     = (const float*)d_in[6];
    const float* gt_cfs   = (const float*)d_in[7];
    const float* gt_amps  = (const float*)d_in[8];
    const float* gt_bws   = (const float*)d_in[9];
    const float* gt_off   = (const float*)d_in[10];
    const float* gt_exp   = (const float*)d_in[11];
    const float* mask     = (const float*)d_in[12];
    float* out = (float*)d_out;

    float* hpart = (float*)d_ws;                 // HBLOCKS floats
    float* rpart = hpart + HBLOCKS;              // 7*RBLOCKS floats

    fused_partial<<<TOTBLOCKS, HTHREADS, 0, stream>>>(
        pred_psd, true_psd, cfs, amps, bws, expn, offs,
        gt_cfs, gt_amps, gt_bws, gt_off, gt_exp, mask, hpart, rpart);
    finalize<<<1, 256, 0, stream>>>(hpart, rpart, out);
}